// Round 9
// baseline (27.811 us; speedup 1.0000x reference)
//
#include <hip/hip_runtime.h>
#include <hip/hip_bf16.h>

// Problem constants
#define BB 32
#define NN 10
#define IN_DIM 65536
#define HEADS 8
#define DD 8
#define ROWS (BB*NN)          // 320
#define MTILES (ROWS/16)      // 20
#define KGRPS 1024            // one block per kgrp -> 4 blocks/CU, 16 waves/CU
#define KB_PER_GRP 2          // 2 MFMA kblocks (32 floats each) per kgrp
#define KFLOATS (KB_PER_GRP*32)   // 64 floats of k per block
#define PAIRS (ROWS*HEADS)    // 2560

typedef __attribute__((ext_vector_type(8))) short bf16x8;
typedef __attribute__((ext_vector_type(4))) float f32x4;

static __device__ __forceinline__ short f2bf(float f) {
    __hip_bfloat16 h = __float2bfloat16(f);
    return *reinterpret_cast<short*>(&h);
}

// ---------------------------------------------------------------------------
// Fused kernel: one block per kgrp (1024 blocks = exactly 4/CU at <=128 VGPR).
// Phase 1: read the block's 16KB W slice, bake bf16 B-fragments (d-summed)
//          into LDS (R6-verified mfma_16x16x32 B layout).
// Phase 2: hold the 2 B-fragments in registers, stream x rows 0..319 for this
//          64-col k-slice (each wave owns 5 mtiles), MFMA, write partials.
// x and W are each read exactly once device-wide.
// ---------------------------------------------------------------------------
__global__ __launch_bounds__(256, 4) void gemv_fused_kernel(const float* __restrict__ x,
                                                            const float* __restrict__ W,
                                                            float* __restrict__ partials) {
    const int kgrp = blockIdx.x;
    const int t    = threadIdx.x;
    const int lane = t & 63;
    const int wave = t >> 6;       // 0..3

    __shared__ bf16x8 lds_b[KB_PER_GRP][64];

    // ---- phase 1: W -> B fragments in LDS (mapping verified in R6) ----
    if (wave < KB_PER_GRP) {
        const int kbl  = wave;           // kblock-local 0..1
        const int head = lane & 15;
        const int kq   = lane >> 4;      // 0..3
        bf16x8 o = {0,0,0,0,0,0,0,0};
        if (head < HEADS) {
            float s0=0,s1=0,s2=0,s3=0,s4=0,s5=0,s6=0,s7=0;
            const float* wbase = W + (size_t)(head * DD) * IN_DIM
                               + kgrp * KFLOATS + kbl * 32 + kq * 8;
#pragma unroll
            for (int d = 0; d < DD; ++d) {
                const float4* p = (const float4*)(wbase + (size_t)d * IN_DIM);
                float4 lo = p[0], hi = p[1];
                s0 += lo.x; s1 += lo.y; s2 += lo.z; s3 += lo.w;
                s4 += hi.x; s5 += hi.y; s6 += hi.z; s7 += hi.w;
            }
            o[0]=f2bf(s0); o[1]=f2bf(s1); o[2]=f2bf(s2); o[3]=f2bf(s3);
            o[4]=f2bf(s4); o[5]=f2bf(s5); o[6]=f2bf(s6); o[7]=f2bf(s7);
        }
        lds_b[kbl][lane] = o;
    }
    __syncthreads();

    const bf16x8 b0 = lds_b[0][lane];
    const bf16x8 b1 = lds_b[1][lane];

    // ---- phase 2: stream x, MFMA per mtile ----
    const int kq   = lane >> 4;
    const int head = lane & 15;
    const int r0   = (lane >> 4) * 4;
    const size_t xoff = (size_t)kgrp * KFLOATS + kq * 8;
    float* pbase = partials + (size_t)kgrp * PAIRS;

#pragma unroll
    for (int m = 0; m < MTILES / 4; ++m) {     // 5 mtiles per wave
        const int mtile = wave * (MTILES / 4) + m;
        const int row   = mtile * 16 + (lane & 15);
        const float* xr = x + (size_t)row * IN_DIM + xoff;

        f32x4 acc = {0.f, 0.f, 0.f, 0.f};
        {
            const float4* p = (const float4*)(xr + 0 * 32);
            float4 lo = p[0], hi = p[1];
            bf16x8 a;
            a[0]=f2bf(lo.x); a[1]=f2bf(lo.y); a[2]=f2bf(lo.z); a[3]=f2bf(lo.w);
            a[4]=f2bf(hi.x); a[5]=f2bf(hi.y); a[6]=f2bf(hi.z); a[7]=f2bf(hi.w);
            acc = __builtin_amdgcn_mfma_f32_16x16x32_bf16(a, b0, acc, 0, 0, 0);
        }
        {
            const float4* p = (const float4*)(xr + 1 * 32);
            float4 lo = p[0], hi = p[1];
            bf16x8 a;
            a[0]=f2bf(lo.x); a[1]=f2bf(lo.y); a[2]=f2bf(lo.z); a[3]=f2bf(lo.w);
            a[4]=f2bf(hi.x); a[5]=f2bf(hi.y); a[6]=f2bf(hi.z); a[7]=f2bf(hi.w);
            acc = __builtin_amdgcn_mfma_f32_16x16x32_bf16(a, b1, acc, 0, 0, 0);
        }

        // C/D layout (m89-verified): col = lane&15 (head), row = (lane>>4)*4 + j
        if (head < HEADS) {
#pragma unroll
            for (int j = 0; j < 4; ++j)
                pbase[(size_t)(mtile * 16 + r0 + j) * HEADS + head] = acc[j];
        }
    }
}

// ---------------------------------------------------------------------------
// Finalize: tot[pair] = sum_g partials[g][pair];  pair = bn*8 + h
//           out[bn][h*10+m] = relu(tot * adj[bn][m])
// 160 blocks x 256 threads: block owns 16 pairs; thread (pr = t&15, gs = t>>4)
// sums 64 of the 1024 kgrps; LDS-fold; first 16 threads write 10 outputs each.
// ---------------------------------------------------------------------------
__global__ __launch_bounds__(256) void finalize_kernel(const float* __restrict__ partials,
                                                       const float* __restrict__ adj,
                                                       float* __restrict__ out) {
    const int b  = blockIdx.x;       // 0..159
    const int t  = threadIdx.x;
    const int pr = t & 15;           // pair-in-block
    const int gs = t >> 4;           // 0..15 (each covers 64 kgrps)
    const int pair = b * 16 + pr;

    float s = 0.f;
    const float* p = partials + (size_t)gs * 64 * PAIRS + pair;
#pragma unroll 8
    for (int g = 0; g < 64; ++g)
        s += p[(size_t)g * PAIRS];

    __shared__ float red[16][16];
    red[gs][pr] = s;
    __syncthreads();

    if (t < 16) {
        float tot = 0.f;
#pragma unroll
        for (int i = 0; i < 16; ++i) tot += red[i][t];
        const int pair2 = b * 16 + t;
        const int bn = pair2 >> 3;
        const int h  = pair2 & 7;
        const float* a = adj + bn * NN;
        float* o = out + bn * (HEADS * NN) + h * NN;
#pragma unroll
        for (int m = 0; m < NN; ++m) {
            float v = tot * a[m];
            o[m] = v > 0.f ? v : 0.f;
        }
    }
}

extern "C" void kernel_launch(void* const* d_in, const int* in_sizes, int n_in,
                              void* d_out, int out_size, void* d_ws, size_t ws_size,
                              hipStream_t stream) {
    const float* x   = (const float*)d_in[0];   // (32,10,65536)
    const float* adj = (const float*)d_in[1];   // (32,10,10)
    const float* W   = (const float*)d_in[2];   // (64,65536)
    float* out = (float*)d_out;                 // (32,10,80)

    // workspace: partials (1024 * 2560 f32 = 10.5 MB)
    float* partials = (float*)d_ws;

    // K1: fused W-bake + MFMA GEMV. 1024 blocks (one per kgrp).
    gemv_fused_kernel<<<KGRPS, 256, 0, stream>>>(x, W, partials);

    // K2: finalize. 160 blocks.
    finalize_kernel<<<160, 256, 0, stream>>>(partials, adj, out);
}

// Round 10
// 26.026 us; speedup vs baseline: 1.0686x; 1.0686x over previous
//
#include <hip/hip_runtime.h>
#include <hip/hip_bf16.h>

// Problem constants
#define BB 32
#define NN 10
#define IN_DIM 65536
#define HEADS 8
#define DD 8
#define ROWS (BB*NN)          // 320
#define MTILES (ROWS/16)      // 20
#define KGRPS 512             // one block per kgrp
#define KB_PER_GRP 4          // 4 MFMA kblocks (32 floats each) per kgrp
#define KFLOATS (KB_PER_GRP*32)   // 128 floats of k per block
#define PAIRS (ROWS*HEADS)    // 2560

typedef __attribute__((ext_vector_type(8))) short bf16x8;
typedef __attribute__((ext_vector_type(4))) float f32x4;
typedef unsigned short u16;

static __device__ __forceinline__ short f2bf(float f) {
    __hip_bfloat16 h = __float2bfloat16(f);
    return *reinterpret_cast<short*>(&h);
}
static __device__ __forceinline__ u16 f2bfu(float f) {
    __hip_bfloat16 h = __float2bfloat16(f);
    return *reinterpret_cast<u16*>(&h);
}
static __device__ __forceinline__ float bf2f(u16 u) {
    unsigned int v = ((unsigned int)u) << 16;
    return *reinterpret_cast<float*>(&v);
}

struct XBuf { float4 a, b, c, d, e, f, g, h; };

static __device__ __forceinline__ XBuf loadx(const float4* q) {
    // q = row base (incl. kq*8 floats). kb-th kblock at float4 idx kb*8 {+0,+1}
    XBuf r;
    r.a = q[0];  r.b = q[1];
    r.c = q[8];  r.d = q[9];
    r.e = q[16]; r.f = q[17];
    r.g = q[24]; r.h = q[25];
    return r;
}

static __device__ __forceinline__ bf16x8 cvt8(float4 lo, float4 hi) {
    bf16x8 a;
    a[0]=f2bf(lo.x); a[1]=f2bf(lo.y); a[2]=f2bf(lo.z); a[3]=f2bf(lo.w);
    a[4]=f2bf(hi.x); a[5]=f2bf(hi.y); a[6]=f2bf(hi.z); a[7]=f2bf(hi.w);
    return a;
}

// ---------------------------------------------------------------------------
// Fused kernel: one block per kgrp (512 blocks = exactly 2/CU, cap 256 VGPR
// so each wave can keep a deep load pipeline -- R9 showed 4x128 regs loses to
// 2x256 because per-wave overhead regs are replicated).
// Phase 1: bake bf16 B-fragments (d-summed W) into LDS (R6-verified layout).
// Phase 2: software-pipelined x stream, 5 mtiles/wave, MFMA, bf16 partials.
// ---------------------------------------------------------------------------
__global__ __launch_bounds__(256, 2) void gemv_fused_kernel(const float* __restrict__ x,
                                                            const float* __restrict__ W,
                                                            u16* __restrict__ partials) {
    const int kgrp = blockIdx.x;
    const int t    = threadIdx.x;
    const int lane = t & 63;
    const int wave = t >> 6;       // 0..3

    __shared__ bf16x8 lds_b[KB_PER_GRP][64];

    // ---- phase 1: W -> B fragments in LDS ----
    {
        const int kbl  = t >> 6;         // kblock-local 0..3
        const int head = lane & 15;
        const int kq   = lane >> 4;      // 0..3
        bf16x8 o = {0,0,0,0,0,0,0,0};
        if (head < HEADS) {
            float s0=0,s1=0,s2=0,s3=0,s4=0,s5=0,s6=0,s7=0;
            const float* wbase = W + (size_t)(head * DD) * IN_DIM
                               + kgrp * KFLOATS + kbl * 32 + kq * 8;
#pragma unroll
            for (int d = 0; d < DD; ++d) {
                const float4* p = (const float4*)(wbase + (size_t)d * IN_DIM);
                float4 lo = p[0], hi = p[1];
                s0 += lo.x; s1 += lo.y; s2 += lo.z; s3 += lo.w;
                s4 += hi.x; s5 += hi.y; s6 += hi.z; s7 += hi.w;
            }
            o[0]=f2bf(s0); o[1]=f2bf(s1); o[2]=f2bf(s2); o[3]=f2bf(s3);
            o[4]=f2bf(s4); o[5]=f2bf(s5); o[6]=f2bf(s6); o[7]=f2bf(s7);
        }
        lds_b[kbl][lane] = o;
    }
    __syncthreads();

    const bf16x8 b0 = lds_b[0][lane];
    const bf16x8 b1 = lds_b[1][lane];
    const bf16x8 b2 = lds_b[2][lane];
    const bf16x8 b3 = lds_b[3][lane];

    // ---- phase 2: software-pipelined x stream ----
    const int head = lane & 15;
    const int r0   = (lane >> 4) * 4;
    const int ln   = lane & 15;
    const int kq   = lane >> 4;
    const size_t xoff = (size_t)kgrp * KFLOATS + kq * 8;
    u16* pbase = partials + (size_t)kgrp * PAIRS;

    const int mt0 = wave * 5;
    const float4* q0 = (const float4*)(x + (size_t)((mt0+0)*16 + ln) * IN_DIM + xoff);
    const float4* q1 = (const float4*)(x + (size_t)((mt0+1)*16 + ln) * IN_DIM + xoff);
    const float4* q2 = (const float4*)(x + (size_t)((mt0+2)*16 + ln) * IN_DIM + xoff);
    const float4* q3 = (const float4*)(x + (size_t)((mt0+3)*16 + ln) * IN_DIM + xoff);
    const float4* q4 = (const float4*)(x + (size_t)((mt0+4)*16 + ln) * IN_DIM + xoff);

    XBuf xb0 = loadx(q0);
    XBuf xb1 = loadx(q1);          // prefetch depth 1

    f32x4 acc;
    // ---- mtile 0 (compute xb0, prefetch q2) ----
    XBuf xb2 = loadx(q2);
    acc = (f32x4){0.f,0.f,0.f,0.f};
    acc = __builtin_amdgcn_mfma_f32_16x16x32_bf16(cvt8(xb0.a, xb0.b), b0, acc, 0,0,0);
    acc = __builtin_amdgcn_mfma_f32_16x16x32_bf16(cvt8(xb0.c, xb0.d), b1, acc, 0,0,0);
    acc = __builtin_amdgcn_mfma_f32_16x16x32_bf16(cvt8(xb0.e, xb0.f), b2, acc, 0,0,0);
    acc = __builtin_amdgcn_mfma_f32_16x16x32_bf16(cvt8(xb0.g, xb0.h), b3, acc, 0,0,0);
    if (head < HEADS) {
#pragma unroll
        for (int j = 0; j < 4; ++j)
            pbase[(size_t)((mt0+0)*16 + r0 + j) * HEADS + head] = f2bfu(acc[j]);
    }
    // ---- mtile 1 (compute xb1, prefetch q3) ----
    XBuf xb3 = loadx(q3);
    acc = (f32x4){0.f,0.f,0.f,0.f};
    acc = __builtin_amdgcn_mfma_f32_16x16x32_bf16(cvt8(xb1.a, xb1.b), b0, acc, 0,0,0);
    acc = __builtin_amdgcn_mfma_f32_16x16x32_bf16(cvt8(xb1.c, xb1.d), b1, acc, 0,0,0);
    acc = __builtin_amdgcn_mfma_f32_16x16x32_bf16(cvt8(xb1.e, xb1.f), b2, acc, 0,0,0);
    acc = __builtin_amdgcn_mfma_f32_16x16x32_bf16(cvt8(xb1.g, xb1.h), b3, acc, 0,0,0);
    if (head < HEADS) {
#pragma unroll
        for (int j = 0; j < 4; ++j)
            pbase[(size_t)((mt0+1)*16 + r0 + j) * HEADS + head] = f2bfu(acc[j]);
    }
    // ---- mtile 2 (compute xb2, prefetch q4) ----
    XBuf xb4 = loadx(q4);
    acc = (f32x4){0.f,0.f,0.f,0.f};
    acc = __builtin_amdgcn_mfma_f32_16x16x32_bf16(cvt8(xb2.a, xb2.b), b0, acc, 0,0,0);
    acc = __builtin_amdgcn_mfma_f32_16x16x32_bf16(cvt8(xb2.c, xb2.d), b1, acc, 0,0,0);
    acc = __builtin_amdgcn_mfma_f32_16x16x32_bf16(cvt8(xb2.e, xb2.f), b2, acc, 0,0,0);
    acc = __builtin_amdgcn_mfma_f32_16x16x32_bf16(cvt8(xb2.g, xb2.h), b3, acc, 0,0,0);
    if (head < HEADS) {
#pragma unroll
        for (int j = 0; j < 4; ++j)
            pbase[(size_t)((mt0+2)*16 + r0 + j) * HEADS + head] = f2bfu(acc[j]);
    }
    // ---- mtile 3 (compute xb3) ----
    acc = (f32x4){0.f,0.f,0.f,0.f};
    acc = __builtin_amdgcn_mfma_f32_16x16x32_bf16(cvt8(xb3.a, xb3.b), b0, acc, 0,0,0);
    acc = __builtin_amdgcn_mfma_f32_16x16x32_bf16(cvt8(xb3.c, xb3.d), b1, acc, 0,0,0);
    acc = __builtin_amdgcn_mfma_f32_16x16x32_bf16(cvt8(xb3.e, xb3.f), b2, acc, 0,0,0);
    acc = __builtin_amdgcn_mfma_f32_16x16x32_bf16(cvt8(xb3.g, xb3.h), b3, acc, 0,0,0);
    if (head < HEADS) {
#pragma unroll
        for (int j = 0; j < 4; ++j)
            pbase[(size_t)((mt0+3)*16 + r0 + j) * HEADS + head] = f2bfu(acc[j]);
    }
    // ---- mtile 4 (compute xb4) ----
    acc = (f32x4){0.f,0.f,0.f,0.f};
    acc = __builtin_amdgcn_mfma_f32_16x16x32_bf16(cvt8(xb4.a, xb4.b), b0, acc, 0,0,0);
    acc = __builtin_amdgcn_mfma_f32_16x16x32_bf16(cvt8(xb4.c, xb4.d), b1, acc, 0,0,0);
    acc = __builtin_amdgcn_mfma_f32_16x16x32_bf16(cvt8(xb4.e, xb4.f), b2, acc, 0,0,0);
    acc = __builtin_amdgcn_mfma_f32_16x16x32_bf16(cvt8(xb4.g, xb4.h), b3, acc, 0,0,0);
    if (head < HEADS) {
#pragma unroll
        for (int j = 0; j < 4; ++j)
            pbase[(size_t)((mt0+4)*16 + r0 + j) * HEADS + head] = f2bfu(acc[j]);
    }
}

// ---------------------------------------------------------------------------
// Finalize: tot[pair] = sum_g partials[g][pair] (bf16);  pair = bn*8 + h
//           out[bn][h*10+m] = relu(tot * adj[bn][m])
// 160 blocks x 256 threads: block owns 16 pairs; thread (pr, gs) sums 32 of
// the 512 kgrps; LDS-fold; first 16 threads write 10 outputs each.
// ---------------------------------------------------------------------------
__global__ __launch_bounds__(256) void finalize_kernel(const u16* __restrict__ partials,
                                                       const float* __restrict__ adj,
                                                       float* __restrict__ out) {
    const int b  = blockIdx.x;       // 0..159
    const int t  = threadIdx.x;
    const int pr = t & 15;           // pair-in-block
    const int gs = t >> 4;           // 0..15 (each covers 32 kgrps)
    const int pair = b * 16 + pr;

    float s = 0.f;
    const u16* p = partials + (size_t)gs * 32 * PAIRS + pair;
#pragma unroll 8
    for (int g = 0; g < 32; ++g)
        s += bf2f(p[(size_t)g * PAIRS]);

    __shared__ float red[16][16];
    red[gs][pr] = s;
    __syncthreads();

    if (t < 16) {
        float tot = 0.f;
#pragma unroll
        for (int i = 0; i < 16; ++i) tot += red[i][t];
        const int pair2 = b * 16 + t;
        const int bn = pair2 >> 3;
        const int h  = pair2 & 7;
        const float* a = adj + bn * NN;
        float* o = out + bn * (HEADS * NN) + h * NN;
#pragma unroll
        for (int m = 0; m < NN; ++m) {
            float v = tot * a[m];
            o[m] = v > 0.f ? v : 0.f;
        }
    }
}

extern "C" void kernel_launch(void* const* d_in, const int* in_sizes, int n_in,
                              void* d_out, int out_size, void* d_ws, size_t ws_size,
                              hipStream_t stream) {
    const float* x   = (const float*)d_in[0];   // (32,10,65536)
    const float* adj = (const float*)d_in[1];   // (32,10,10)
    const float* W   = (const float*)d_in[2];   // (64,65536)
    float* out = (float*)d_out;                 // (32,10,80)

    // workspace: partials (512 * 2560 bf16 = 2.62 MB)
    u16* partials = (u16*)d_ws;

    // K1: fused W-bake + MFMA GEMV. 512 blocks (one per kgrp).
    gemv_fused_kernel<<<KGRPS, 256, 0, stream>>>(x, W, partials);

    // K2: finalize. 160 blocks.
    finalize_kernel<<<160, 256, 0, stream>>>(partials, adj, out);
}